// Round 18
// baseline (694.151 us; speedup 1.0000x reference)
//
#include <hip/hip_runtime.h>
#include <stdint.h>

// Round 18: R17 full fusion + the spill fix. R17's 693us was SCRATCH SPILL:
// __launch_bounds__(768) without min-waves let the compiler target 2 blocks/CU
// -> 85-VGPR cap -> acck[4][4] spilled -> 1.36GB scratch writes. LDS=99KB makes
// this kernel 1 block/CU regardless, so __launch_bounds__(768,3) (3 waves/SIMD
// = 12 waves = 1 block) raises the budget to ~170 VGPR -> no spill. Math
// byte-identical to R17 (passed, absmax 0.0078).

typedef __attribute__((ext_vector_type(4))) float f32x4;
typedef __attribute__((ext_vector_type(4))) short s16x4;
typedef __attribute__((ext_vector_type(8))) short s16x8;

#define DEVI static __device__ __forceinline__

DEVI unsigned short f2bf(float f) {
  union { float f; uint32_t u; } v; v.f = f;
  return (unsigned short)((v.u + 0x7FFFu + ((v.u >> 16) & 1u)) >> 16);
}

DEVI uint32_t pk2(float lo, float hi) {
  return (uint32_t)f2bf(lo) | ((uint32_t)f2bf(hi) << 16);
}

DEVI f32x4 zero4() { f32x4 z; z[0] = 0.f; z[1] = 0.f; z[2] = 0.f; z[3] = 0.f; return z; }

#if defined(__has_builtin)
#if __has_builtin(__builtin_amdgcn_mfma_f32_16x16x16bf16_1k)
#define MFMA16_BUILTIN 1
#endif
#if __has_builtin(__builtin_amdgcn_global_load_lds)
#define HAS_GLLDS 1
#endif
#endif

DEVI f32x4 mfma16(s16x4 a, s16x4 b, f32x4 c) {
#ifdef MFMA16_BUILTIN
  return __builtin_amdgcn_mfma_f32_16x16x16bf16_1k(a, b, c, 0, 0, 0);
#else
  asm volatile("v_mfma_f32_16x16x16_bf16 %0, %1, %2, %0" : "+v"(c) : "v"(a), "v"(b));
  return c;
#endif
}

DEVI f32x4 mfma32(s16x8 a, s16x8 b, f32x4 c) {
  return __builtin_amdgcn_mfma_f32_16x16x32_bf16(a, b, c, 0, 0, 0);
}

DEVI void stage1k(const unsigned short* g_lane, unsigned short* lds_base) {
#ifdef HAS_GLLDS
  __builtin_amdgcn_global_load_lds(
      (const __attribute__((address_space(1))) unsigned int*)g_lane,
      (__attribute__((address_space(3))) unsigned int*)lds_base, 16, 0, 0);
#else
  *(s16x8*)(lds_base + (threadIdx.x & 63) * 8) = *(const s16x8*)g_lane;
#endif
}

__global__ void fill_val(float* o, int n, float v) {
  int t = blockIdx.x * 256 + threadIdx.x;
  if (t < n) o[t] = v;
}

// ---------------- merged prep (R13 verbatim) ----------------
__global__ __launch_bounds__(256) void prep_all(
    const float* __restrict__ x, unsigned short* __restrict__ xb,
    const float* __restrict__ Wqkv, unsigned short* __restrict__ WqkvT,
    const float* __restrict__ Wm, unsigned short* __restrict__ WmT,
    const float* __restrict__ bqkv, float* __restrict__ bqkvs,
    const float* __restrict__ rel, float* __restrict__ biasF) {
  const int b = blockIdx.x;
  if (b < 2048) {
    const size_t nchunk = 131072UL * 384 / 8;
    for (size_t i = (size_t)b * 256 + threadIdx.x; i < nchunk; i += 2048UL * 256) {
      f32x4 a = *(const f32x4*)(x + i * 8);
      f32x4 c = *(const f32x4*)(x + i * 8 + 4);
      s16x8 p;
      p[0] = (short)f2bf(a[0]); p[1] = (short)f2bf(a[1]);
      p[2] = (short)f2bf(a[2]); p[3] = (short)f2bf(a[3]);
      p[4] = (short)f2bf(c[0]); p[5] = (short)f2bf(c[1]);
      p[6] = (short)f2bf(c[2]); p[7] = (short)f2bf(c[3]);
      *(s16x8*)(xb + i * 8) = p;
    }
  } else if (b == 2048) {
    for (int t = threadIdx.x; t < 1152; t += 256)
      bqkvs[t] = bqkv[t] * ((t < 384) ? 0.17677669529663687f : 1.0f);
  } else if (b < 2097) {
    int t = (b - 2049) * 256 + threadIdx.x;  // 12288
    if (t < 12288) {
      int h = t >> 10;
      int r = (t >> 6) & 15;
      int lane = t & 63;
      int jt = r >> 2, it = r & 3;
      int lg = lane >> 4, lr = lane & 15;
      int i = it * 16 + lr;
#pragma unroll
      for (int e = 0; e < 4; ++e) {
        int j = jt * 16 + lg * 4 + e;
        int idx = ((i >> 3) - (j >> 3) + 7) * 15 + ((i & 7) - (j & 7) + 7);
        biasF[t * 4 + e] = rel[idx * 12 + h];
      }
    }
  } else if (b < 2673) {
    int t = (b - 2097) * 256 + threadIdx.x;  // 147456
    int n = t / 384, k = t - n * 384;
    WmT[t] = f2bf(Wm[(size_t)k * 384 + n]);
  } else {
    int t = (b - 2673) * 256 + threadIdx.x;  // 442368
    int n = t / 384, k = t - n * 384;
    float s = (n < 384) ? 0.17677669529663687f : 1.0f;
    WqkvT[t] = f2bf(Wqkv[(size_t)k * 1152 + n] * s);
  }
}

// ---------------- fully fused: gemm1 + attention + gemm2, one block/window -------
__global__ __launch_bounds__(768, 3) void fused_k(const unsigned short* __restrict__ xb,
                                                  const unsigned short* __restrict__ WqkvT,
                                                  const float* __restrict__ bqkvs,
                                                  const float* __restrict__ biasF,
                                                  const unsigned short* __restrict__ WmT,
                                                  const float* __restrict__ bm,
                                                  float* __restrict__ out) {
  __shared__ __attribute__((aligned(16))) unsigned short smem[49664];
  unsigned short* x_s = smem;
  unsigned short* qks = smem;
  unsigned short* att_s = smem;

  const int lane = threadIdx.x & 63;
  const int wv = threadIdx.x >> 6;  // 0..11; attn phase: head wv
  const int window = blockIdx.x;    // [0, 2048)
  const int lg = lane >> 4, lr = lane & 15;

  // ---- stage x tile: row r = one 1KB wave-call; LDS chunk l <- global chunk l^(r&7)
  for (int r = wv; r < 64; r += 12) {
    const unsigned short* src =
        xb + (size_t)(window * 64 + r) * 384 + (size_t)((lane ^ (r & 7)) * 8);
    stage1k(src, &x_s[r * 512]);
  }
  __syncthreads();  // drains vmcnt (order-independent)

  // A-frag read helper: global chunk c of row -> LDS chunk c^(lr&7)  (row&7 == lr&7)
#define AF(mt, ks) \
  (*(const s16x8*)&x_s[(16 * (mt) + lr) * 512 + (((ks) * 4 + lg) ^ (lr & 7)) * 8])

  // ---- pass V: wave wv -> head wv's V cols (WqkvT rows 768+wv*32 .. +32)
  f32x4 accv[4][2];
#pragma unroll
  for (int mt = 0; mt < 4; ++mt)
#pragma unroll
    for (int nt = 0; nt < 2; ++nt) accv[mt][nt] = zero4();
  {
    const unsigned short* W0 = WqkvT + (size_t)(768 + wv * 32 + lr) * 384 + 8 * lg;
    const unsigned short* W1 = W0 + (size_t)16 * 384;
#pragma unroll
    for (int ks = 0; ks < 12; ++ks) {
      s16x8 bf0 = *(const s16x8*)(W0 + ks * 32);
      s16x8 bf1 = *(const s16x8*)(W1 + ks * 32);
#pragma unroll
      for (int mt = 0; mt < 4; ++mt) {
        s16x8 a = AF(mt, ks);
        accv[mt][0] = mfma32(a, bf0, accv[mt][0]);
        accv[mt][1] = mfma32(a, bf1, accv[mt][1]);
      }
    }
  }
  // bias + pack: va[jt][dt] = V[token=16jt+4lg+e][d=16dt+lr]  (direct PV A-frag)
  s16x4 va[4][2];
#pragma unroll
  for (int dt = 0; dt < 2; ++dt) {
    const float bv = bqkvs[768 + wv * 32 + dt * 16 + lr];
#pragma unroll
    for (int jt = 0; jt < 4; ++jt) {
      s16x4 pk;
#pragma unroll
      for (int e = 0; e < 4; ++e) pk[e] = (short)f2bf(accv[jt][dt][e] + bv);
      va[jt][dt] = pk;
    }
  }

  // ---- pass QK: wave wv -> qkcols [wv*64, wv*64+64)  (WqkvT rows 0..767)
  f32x4 acck[4][4];
#pragma unroll
  for (int mt = 0; mt < 4; ++mt)
#pragma unroll
    for (int nt = 0; nt < 4; ++nt) acck[mt][nt] = zero4();
  {
    const unsigned short* Wq = WqkvT + (size_t)(wv * 64 + lr) * 384 + 8 * lg;
#pragma unroll
    for (int ks = 0; ks < 12; ++ks) {
      s16x8 bf[4];
#pragma unroll
      for (int nt = 0; nt < 4; ++nt)
        bf[nt] = *(const s16x8*)(Wq + (size_t)(16 * nt) * 384 + ks * 32);
#pragma unroll
      for (int mt = 0; mt < 4; ++mt) {
        s16x8 a = AF(mt, ks);
#pragma unroll
        for (int nt = 0; nt < 4; ++nt) acck[mt][nt] = mfma32(a, bf[nt], acck[mt][nt]);
      }
    }
  }
  __syncthreads();  // x_s dead; qks space safe to write

  // ---- bounce Q,K -> qks[token][qkcol], stride 776 (word stride ≡ 4 mod 32)
#pragma unroll
  for (int nt = 0; nt < 4; ++nt) {
    const int qkcol = wv * 64 + 16 * nt + lr;
    const float bv = bqkvs[qkcol];
#pragma unroll
    for (int mt = 0; mt < 4; ++mt)
#pragma unroll
      for (int e = 0; e < 4; ++e)
        qks[(16 * mt + 4 * lg + e) * 776 + qkcol] = f2bf(acck[mt][nt][e] + bv);
  }
  __syncthreads();  // qks ready

  // ---- attn frags for head wv
  s16x8 ka[4], qb[4];
#pragma unroll
  for (int jt = 0; jt < 4; ++jt)
    ka[jt] = *(const s16x8*)&qks[(16 * jt + lr) * 776 + 384 + wv * 32 + 8 * lg];
#pragma unroll
  for (int it = 0; it < 4; ++it)
    qb[it] = *(const s16x8*)&qks[(16 * it + lr) * 776 + wv * 32 + 8 * lg];
  __syncthreads();  // all frags read; qks dead (att_s overlaps)

  // ---- attention (R15 verbatim math)
  f32x4 c[4][4];
#pragma unroll
  for (int a = 0; a < 4; ++a)
#pragma unroll
    for (int b2 = 0; b2 < 4; ++b2) c[a][b2] = zero4();

#pragma unroll
  for (int jt = 0; jt < 4; ++jt)
#pragma unroll
    for (int it = 0; it < 4; ++it)
      c[jt][it] = mfma32(ka[jt], qb[it], c[jt][it]);

  const f32x4* bF = (const f32x4*)biasF + ((size_t)wv * 16) * 64 + lane;
#pragma unroll
  for (int jt = 0; jt < 4; ++jt)
#pragma unroll
    for (int it = 0; it < 4; ++it)
      c[jt][it] += bF[(jt * 4 + it) * 64];

  s16x4 pb[4][4];
#pragma unroll
  for (int it = 0; it < 4; ++it) {
    float m = -3.0e38f;
#pragma unroll
    for (int jt = 0; jt < 4; ++jt)
#pragma unroll
      for (int e = 0; e < 4; ++e) m = fmaxf(m, c[jt][it][e]);
    m = fmaxf(m, __shfl_xor(m, 16));
    m = fmaxf(m, __shfl_xor(m, 32));
    float s = 0.f;
#pragma unroll
    for (int jt = 0; jt < 4; ++jt)
#pragma unroll
      for (int e = 0; e < 4; ++e) {
        float p = __expf(c[jt][it][e] - m);
        c[jt][it][e] = p;
        s += p;
      }
    s += __shfl_xor(s, 16);
    s += __shfl_xor(s, 32);
    const float inv = 1.f / s;
#pragma unroll
    for (int jt = 0; jt < 4; ++jt) {
      s16x4 pk;
#pragma unroll
      for (int e = 0; e < 4; ++e) pk[e] = (short)f2bf(c[jt][it][e] * inv);
      pb[jt][it] = pk;
    }
  }

  f32x4 o[2][4];
#pragma unroll
  for (int a = 0; a < 2; ++a)
#pragma unroll
    for (int b2 = 0; b2 < 4; ++b2) o[a][b2] = zero4();

#pragma unroll
  for (int jt = 0; jt < 4; ++jt)
#pragma unroll
    for (int dt = 0; dt < 2; ++dt)
#pragma unroll
      for (int it = 0; it < 4; ++it)
        o[dt][it] = mfma16(va[jt][dt], pb[jt][it], o[dt][it]);

  // ---- R14 4-lane transpose -> att_s
#pragma unroll
  for (int it = 0; it < 4; ++it) {
    const uint32_t p0 = pk2(o[0][it][0], o[0][it][1]);
    const uint32_t p1 = pk2(o[0][it][2], o[0][it][3]);
    const uint32_t q0 = pk2(o[1][it][0], o[1][it][1]);
    const uint32_t q1 = pk2(o[1][it][2], o[1][it][3]);

    const uint32_t x16_0 = __shfl_xor((int)(lg == 2 ? q0 : p0), 16);
    const uint32_t x16_1 = __shfl_xor((int)(lg == 2 ? q1 : p1), 16);
    const uint32_t x32_0 = __shfl_xor((int)(lg == 0 ? q0 : p0), 32);
    const uint32_t x32_1 = __shfl_xor((int)(lg == 0 ? q1 : p1), 32);
    const uint32_t x48_0 = __shfl_xor((int)(lg == 1 ? q0 : p0), 48);
    const uint32_t x48_1 = __shfl_xor((int)(lg == 1 ? q1 : p1), 48);

    uint32_t w[4];
    w[0] = lg == 0 ? p0 : lg == 1 ? x48_0 : lg == 2 ? x32_0 : x16_0;
    w[1] = lg == 0 ? p1 : lg == 1 ? x48_1 : lg == 2 ? x32_1 : x16_1;
    w[2] = lg == 0 ? x16_0 : lg == 1 ? x32_0 : lg == 2 ? x48_0 : q0;
    w[3] = lg == 0 ? x16_1 : lg == 1 ? x32_1 : lg == 2 ? x48_1 : q1;

    *(uint4*)&att_s[(size_t)(it * 16 + lr) * 392 + wv * 32 + 8 * lg] =
        make_uint4(w[0], w[1], w[2], w[3]);
  }

  __syncthreads();

  // ---- phase 2: GEMM2 (R15 verbatim). wave wv -> cols [wv*32, +32)
  f32x4 acc[4][2];
#pragma unroll
  for (int mt = 0; mt < 4; ++mt)
#pragma unroll
    for (int nt = 0; nt < 2; ++nt) acc[mt][nt] = zero4();

  const int n0w = wv * 32;
#pragma unroll 2
  for (int ks = 0; ks < 12; ++ks) {
    s16x8 af[4], bf[2];
#pragma unroll
    for (int mt = 0; mt < 4; ++mt)
      af[mt] = *(const s16x8*)&att_s[(16 * mt + lr) * 392 + ks * 32 + 8 * lg];
#pragma unroll
    for (int nt = 0; nt < 2; ++nt)
      bf[nt] = *(const s16x8*)&WmT[(size_t)(n0w + 16 * nt + lr) * 384 + ks * 32 + 8 * lg];
#pragma unroll
    for (int mt = 0; mt < 4; ++mt)
#pragma unroll
      for (int nt = 0; nt < 2; ++nt)
        acc[mt][nt] = mfma32(af[mt], bf[nt], acc[mt][nt]);
  }

  float* ob = out + (size_t)window * 64 * 384;
#pragma unroll
  for (int mt = 0; mt < 4; ++mt)
#pragma unroll
    for (int nt = 0; nt < 2; ++nt) {
      const int col = n0w + 16 * nt + lr;
      const float bv = bm[col];
#pragma unroll
      for (int e = 0; e < 4; ++e)
        ob[(size_t)(16 * mt + 4 * lg + e) * 384 + col] = acc[mt][nt][e] + bv;
    }
#undef AF
}

extern "C" void kernel_launch(void* const* d_in, const int* in_sizes, int n_in,
                              void* d_out, int out_size, void* d_ws, size_t ws_size,
                              hipStream_t stream) {
  const float* x = (const float*)d_in[0];
  const float* Wqkv = (const float*)d_in[1];
  const float* bqkv = (const float*)d_in[2];
  const float* Wm = (const float*)d_in[3];
  const float* bm = (const float*)d_in[4];
  const float* rel = (const float*)d_in[5];

  const size_t M = 131072;  // B*G*P
  char* ws = (char*)d_ws;
  size_t off = 0;
  unsigned short* xb = (unsigned short*)(ws + off);    off += M * 384 * 2;  // 100 MB
  unsigned short* WqkvT = (unsigned short*)(ws + off); off += 1152 * 384 * 2;
  unsigned short* WmT = (unsigned short*)(ws + off);   off += 384 * 384 * 2;
  float* biasF = (float*)(ws + off);                   off += 12 * 16 * 64 * 4 * 4;
  float* bqkvs = (float*)(ws + off);                   off += 1152 * 4;
  off += 1024;  // slack for the staging over-read at xb end

  if (ws_size < off) {
    fill_val<<<(out_size + 255) / 256, 256, 0, stream>>>((float*)d_out, out_size, 12345.0f);
    return;
  }

  prep_all<<<4401, 256, 0, stream>>>(x, xb, Wqkv, WqkvT, Wm, WmT, bqkv, bqkvs, rel, biasF);
  fused_k<<<2048, 768, 0, stream>>>(xb, WqkvT, bqkvs, biasF, WmT, bm, (float*)d_out);
}

// Round 19
// 664.100 us; speedup vs baseline: 1.0453x; 1.0453x over previous
//
#include <hip/hip_runtime.h>
#include <stdint.h>

// Round 19: full fusion, spill fixed STRUCTURALLY. R17/18 spilled (1.36GB
// scratch) because acck[4][4] had to stay live across the whole QK pass —
// the Q/K LDS bounce had to wait for x_s to die (qks aliased x_s). Fix:
// padded x_s[64][392] (50KB, reg-staged ds_write, stride ≡4 mod 32 -> 2-way
// free, no swizzle) + qks[64][776] (97KB) DISJOINT (149.5KB <= 160KB LDS).
// QK runs as two acck[4][2] sub-passes, each bounced to qks immediately ->
// peak pressure ~= attn phase (R15-proven 56-60 VGPR, no spill).

typedef __attribute__((ext_vector_type(4))) float f32x4;
typedef __attribute__((ext_vector_type(4))) short s16x4;
typedef __attribute__((ext_vector_type(8))) short s16x8;

#define DEVI static __device__ __forceinline__

DEVI unsigned short f2bf(float f) {
  union { float f; uint32_t u; } v; v.f = f;
  return (unsigned short)((v.u + 0x7FFFu + ((v.u >> 16) & 1u)) >> 16);
}

DEVI uint32_t pk2(float lo, float hi) {
  return (uint32_t)f2bf(lo) | ((uint32_t)f2bf(hi) << 16);
}

DEVI f32x4 zero4() { f32x4 z; z[0] = 0.f; z[1] = 0.f; z[2] = 0.f; z[3] = 0.f; return z; }

#if defined(__has_builtin)
#if __has_builtin(__builtin_amdgcn_mfma_f32_16x16x16bf16_1k)
#define MFMA16_BUILTIN 1
#endif
#endif

DEVI f32x4 mfma16(s16x4 a, s16x4 b, f32x4 c) {
#ifdef MFMA16_BUILTIN
  return __builtin_amdgcn_mfma_f32_16x16x16bf16_1k(a, b, c, 0, 0, 0);
#else
  asm volatile("v_mfma_f32_16x16x16_bf16 %0, %1, %2, %0" : "+v"(c) : "v"(a), "v"(b));
  return c;
#endif
}

DEVI f32x4 mfma32(s16x8 a, s16x8 b, f32x4 c) {
  return __builtin_amdgcn_mfma_f32_16x16x32_bf16(a, b, c, 0, 0, 0);
}

__global__ void fill_val(float* o, int n, float v) {
  int t = blockIdx.x * 256 + threadIdx.x;
  if (t < n) o[t] = v;
}

// ---------------- merged prep (R13 verbatim) ----------------
__global__ __launch_bounds__(256) void prep_all(
    const float* __restrict__ x, unsigned short* __restrict__ xb,
    const float* __restrict__ Wqkv, unsigned short* __restrict__ WqkvT,
    const float* __restrict__ Wm, unsigned short* __restrict__ WmT,
    const float* __restrict__ bqkv, float* __restrict__ bqkvs,
    const float* __restrict__ rel, float* __restrict__ biasF) {
  const int b = blockIdx.x;
  if (b < 2048) {
    const size_t nchunk = 131072UL * 384 / 8;
    for (size_t i = (size_t)b * 256 + threadIdx.x; i < nchunk; i += 2048UL * 256) {
      f32x4 a = *(const f32x4*)(x + i * 8);
      f32x4 c = *(const f32x4*)(x + i * 8 + 4);
      s16x8 p;
      p[0] = (short)f2bf(a[0]); p[1] = (short)f2bf(a[1]);
      p[2] = (short)f2bf(a[2]); p[3] = (short)f2bf(a[3]);
      p[4] = (short)f2bf(c[0]); p[5] = (short)f2bf(c[1]);
      p[6] = (short)f2bf(c[2]); p[7] = (short)f2bf(c[3]);
      *(s16x8*)(xb + i * 8) = p;
    }
  } else if (b == 2048) {
    for (int t = threadIdx.x; t < 1152; t += 256)
      bqkvs[t] = bqkv[t] * ((t < 384) ? 0.17677669529663687f : 1.0f);
  } else if (b < 2097) {
    int t = (b - 2049) * 256 + threadIdx.x;  // 12288
    if (t < 12288) {
      int h = t >> 10;
      int r = (t >> 6) & 15;
      int lane = t & 63;
      int jt = r >> 2, it = r & 3;
      int lg = lane >> 4, lr = lane & 15;
      int i = it * 16 + lr;
#pragma unroll
      for (int e = 0; e < 4; ++e) {
        int j = jt * 16 + lg * 4 + e;
        int idx = ((i >> 3) - (j >> 3) + 7) * 15 + ((i & 7) - (j & 7) + 7);
        biasF[t * 4 + e] = rel[idx * 12 + h];
      }
    }
  } else if (b < 2673) {
    int t = (b - 2097) * 256 + threadIdx.x;  // 147456
    int n = t / 384, k = t - n * 384;
    WmT[t] = f2bf(Wm[(size_t)k * 384 + n]);
  } else {
    int t = (b - 2673) * 256 + threadIdx.x;  // 442368
    int n = t / 384, k = t - n * 384;
    float s = (n < 384) ? 0.17677669529663687f : 1.0f;
    WqkvT[t] = f2bf(Wqkv[(size_t)k * 1152 + n] * s);
  }
}

// ---------------- fully fused: gemm1 + attention + gemm2, one block/window -------
// LDS (149504 B): x_s[64][392] @0 (50176B, padded stride, lives through V pass);
// qks[64][776] @25088 shorts (99328B, disjoint from x_s); att_s aliases qks.
__global__ __launch_bounds__(768) void fused_k(const unsigned short* __restrict__ xb,
                                               const unsigned short* __restrict__ WqkvT,
                                               const float* __restrict__ bqkvs,
                                               const float* __restrict__ biasF,
                                               const unsigned short* __restrict__ WmT,
                                               const float* __restrict__ bm,
                                               float* __restrict__ out) {
  __shared__ __attribute__((aligned(16))) unsigned short smem[74752];
  unsigned short* x_s = smem;            // [64][392]
  unsigned short* qks = smem + 25088;    // [64][776]
  unsigned short* att_s = smem + 25088;  // [64][392], after qks dies

  const int lane = threadIdx.x & 63;
  const int wv = threadIdx.x >> 6;  // 0..11; attn phase: head wv
  const int window = blockIdx.x;    // [0, 2048)
  const int lg = lane >> 4, lr = lane & 15;

  // ---- stage x tile (reg-staged, padded): chunk c = tid + 768*i, row=c/48, col=c%48
  {
    const unsigned short* xt = xb + (size_t)window * 64 * 384;
#pragma unroll
    for (int i = 0; i < 4; ++i) {
      const int c = threadIdx.x + 768 * i;  // 0..3071
      const int row = c / 48, col = c - row * 48;
      s16x8 v = *(const s16x8*)(xt + (size_t)c * 8);
      *(s16x8*)&x_s[row * 392 + col * 8] = v;
    }
  }
  __syncthreads();

  // A-frag: rows 16mt+lr, k-chunk ks*4+lg (stride 392 ≡ 4 mod 32 words -> 2-way free)
#define AF(mt, ks) (*(const s16x8*)&x_s[(16 * (mt) + lr) * 392 + ((ks) * 4 + lg) * 8])

  // ---- QK pass: two sub-passes of 32 cols; bounce to qks IMMEDIATELY (disjoint LDS)
#pragma unroll 1
  for (int p = 0; p < 2; ++p) {
    f32x4 acck[4][2];
#pragma unroll
    for (int mt = 0; mt < 4; ++mt)
#pragma unroll
      for (int nt = 0; nt < 2; ++nt) acck[mt][nt] = zero4();
    const unsigned short* Wq = WqkvT + (size_t)(wv * 64 + p * 32 + lr) * 384 + 8 * lg;
#pragma unroll
    for (int ks = 0; ks < 12; ++ks) {
      s16x8 bf0 = *(const s16x8*)(Wq + ks * 32);
      s16x8 bf1 = *(const s16x8*)(Wq + (size_t)16 * 384 + ks * 32);
#pragma unroll
      for (int mt = 0; mt < 4; ++mt) {
        s16x8 a = AF(mt, ks);
        acck[mt][0] = mfma32(a, bf0, acck[mt][0]);
        acck[mt][1] = mfma32(a, bf1, acck[mt][1]);
      }
    }
    // bounce: qks[token][qkcol], stride 776
#pragma unroll
    for (int nt = 0; nt < 2; ++nt) {
      const int qkcol = wv * 64 + p * 32 + nt * 16 + lr;
      const float bv = bqkvs[qkcol];
#pragma unroll
      for (int mt = 0; mt < 4; ++mt)
#pragma unroll
        for (int e = 0; e < 4; ++e)
          qks[(16 * mt + 4 * lg + e) * 776 + qkcol] = f2bf(acck[mt][nt][e] + bv);
    }
  }

  // ---- V pass (x_s still alive — disjoint from qks)
  s16x4 va[4][2];
  {
    f32x4 accv[4][2];
#pragma unroll
    for (int mt = 0; mt < 4; ++mt)
#pragma unroll
      for (int nt = 0; nt < 2; ++nt) accv[mt][nt] = zero4();
    const unsigned short* W0 = WqkvT + (size_t)(768 + wv * 32 + lr) * 384 + 8 * lg;
    const unsigned short* W1 = W0 + (size_t)16 * 384;
#pragma unroll
    for (int ks = 0; ks < 12; ++ks) {
      s16x8 bf0 = *(const s16x8*)(W0 + ks * 32);
      s16x8 bf1 = *(const s16x8*)(W1 + ks * 32);
#pragma unroll
      for (int mt = 0; mt < 4; ++mt) {
        s16x8 a = AF(mt, ks);
        accv[mt][0] = mfma32(a, bf0, accv[mt][0]);
        accv[mt][1] = mfma32(a, bf1, accv[mt][1]);
      }
    }
    // va[jt][dt] = V[token=16jt+4lg+e][d=16dt+lr] — direct PV A-frag (C-layout identity)
#pragma unroll
    for (int dt = 0; dt < 2; ++dt) {
      const float bv = bqkvs[768 + wv * 32 + dt * 16 + lr];
#pragma unroll
      for (int jt = 0; jt < 4; ++jt) {
        s16x4 pk;
#pragma unroll
        for (int e = 0; e < 4; ++e) pk[e] = (short)f2bf(accv[jt][dt][e] + bv);
        va[jt][dt] = pk;
      }
    }
  }
  __syncthreads();  // all waves' qks bounces complete

  // ---- attn frags for head wv
  s16x8 ka[4], qb[4];
#pragma unroll
  for (int jt = 0; jt < 4; ++jt)
    ka[jt] = *(const s16x8*)&qks[(16 * jt + lr) * 776 + 384 + wv * 32 + 8 * lg];
#pragma unroll
  for (int it = 0; it < 4; ++it)
    qb[it] = *(const s16x8*)&qks[(16 * it + lr) * 776 + wv * 32 + 8 * lg];
  __syncthreads();  // frags read; qks dead (att_s aliases)

  // ---- attention (R15 verbatim math)
  f32x4 c[4][4];
#pragma unroll
  for (int a = 0; a < 4; ++a)
#pragma unroll
    for (int b2 = 0; b2 < 4; ++b2) c[a][b2] = zero4();

#pragma unroll
  for (int jt = 0; jt < 4; ++jt)
#pragma unroll
    for (int it = 0; it < 4; ++it)
      c[jt][it] = mfma32(ka[jt], qb[it], c[jt][it]);

  const f32x4* bF = (const f32x4*)biasF + ((size_t)wv * 16) * 64 + lane;
#pragma unroll
  for (int jt = 0; jt < 4; ++jt)
#pragma unroll
    for (int it = 0; it < 4; ++it)
      c[jt][it] += bF[(jt * 4 + it) * 64];

  s16x4 pb[4][4];
#pragma unroll
  for (int it = 0; it < 4; ++it) {
    float m = -3.0e38f;
#pragma unroll
    for (int jt = 0; jt < 4; ++jt)
#pragma unroll
      for (int e = 0; e < 4; ++e) m = fmaxf(m, c[jt][it][e]);
    m = fmaxf(m, __shfl_xor(m, 16));
    m = fmaxf(m, __shfl_xor(m, 32));
    float s = 0.f;
#pragma unroll
    for (int jt = 0; jt < 4; ++jt)
#pragma unroll
      for (int e = 0; e < 4; ++e) {
        float p = __expf(c[jt][it][e] - m);
        c[jt][it][e] = p;
        s += p;
      }
    s += __shfl_xor(s, 16);
    s += __shfl_xor(s, 32);
    const float inv = 1.f / s;
#pragma unroll
    for (int jt = 0; jt < 4; ++jt) {
      s16x4 pk;
#pragma unroll
      for (int e = 0; e < 4; ++e) pk[e] = (short)f2bf(c[jt][it][e] * inv);
      pb[jt][it] = pk;
    }
  }

  f32x4 o[2][4];
#pragma unroll
  for (int a = 0; a < 2; ++a)
#pragma unroll
    for (int b2 = 0; b2 < 4; ++b2) o[a][b2] = zero4();

#pragma unroll
  for (int jt = 0; jt < 4; ++jt)
#pragma unroll
    for (int dt = 0; dt < 2; ++dt)
#pragma unroll
      for (int it = 0; it < 4; ++it)
        o[dt][it] = mfma16(va[jt][dt], pb[jt][it], o[dt][it]);

  // ---- R14 4-lane transpose -> att_s
#pragma unroll
  for (int it = 0; it < 4; ++it) {
    const uint32_t p0 = pk2(o[0][it][0], o[0][it][1]);
    const uint32_t p1 = pk2(o[0][it][2], o[0][it][3]);
    const uint32_t q0 = pk2(o[1][it][0], o[1][it][1]);
    const uint32_t q1 = pk2(o[1][it][2], o[1][it][3]);

    const uint32_t x16_0 = __shfl_xor((int)(lg == 2 ? q0 : p0), 16);
    const uint32_t x16_1 = __shfl_xor((int)(lg == 2 ? q1 : p1), 16);
    const uint32_t x32_0 = __shfl_xor((int)(lg == 0 ? q0 : p0), 32);
    const uint32_t x32_1 = __shfl_xor((int)(lg == 0 ? q1 : p1), 32);
    const uint32_t x48_0 = __shfl_xor((int)(lg == 1 ? q0 : p0), 48);
    const uint32_t x48_1 = __shfl_xor((int)(lg == 1 ? q1 : p1), 48);

    uint32_t w[4];
    w[0] = lg == 0 ? p0 : lg == 1 ? x48_0 : lg == 2 ? x32_0 : x16_0;
    w[1] = lg == 0 ? p1 : lg == 1 ? x48_1 : lg == 2 ? x32_1 : x16_1;
    w[2] = lg == 0 ? x16_0 : lg == 1 ? x32_0 : lg == 2 ? x48_0 : q0;
    w[3] = lg == 0 ? x16_1 : lg == 1 ? x32_1 : lg == 2 ? x48_1 : q1;

    *(uint4*)&att_s[(size_t)(it * 16 + lr) * 392 + wv * 32 + 8 * lg] =
        make_uint4(w[0], w[1], w[2], w[3]);
  }

  __syncthreads();

  // ---- phase 2: GEMM2 (R15 verbatim). wave wv -> cols [wv*32, +32)
  f32x4 acc[4][2];
#pragma unroll
  for (int mt = 0; mt < 4; ++mt)
#pragma unroll
    for (int nt = 0; nt < 2; ++nt) acc[mt][nt] = zero4();

  const int n0w = wv * 32;
#pragma unroll 2
  for (int ks = 0; ks < 12; ++ks) {
    s16x8 af[4], bf[2];
#pragma unroll
    for (int mt = 0; mt < 4; ++mt)
      af[mt] = *(const s16x8*)&att_s[(16 * mt + lr) * 392 + ks * 32 + 8 * lg];
#pragma unroll
    for (int nt = 0; nt < 2; ++nt)
      bf[nt] = *(const s16x8*)&WmT[(size_t)(n0w + 16 * nt + lr) * 384 + ks * 32 + 8 * lg];
#pragma unroll
    for (int mt = 0; mt < 4; ++mt)
#pragma unroll
      for (int nt = 0; nt < 2; ++nt)
        acc[mt][nt] = mfma32(af[mt], bf[nt], acc[mt][nt]);
  }

  float* ob = out + (size_t)window * 64 * 384;
#pragma unroll
  for (int mt = 0; mt < 4; ++mt)
#pragma unroll
    for (int nt = 0; nt < 2; ++nt) {
      const int col = n0w + 16 * nt + lr;
      const float bv = bm[col];
#pragma unroll
      for (int e = 0; e < 4; ++e)
        ob[(size_t)(16 * mt + 4 * lg + e) * 384 + col] = acc[mt][nt][e] + bv;
    }
#undef AF
}

extern "C" void kernel_launch(void* const* d_in, const int* in_sizes, int n_in,
                              void* d_out, int out_size, void* d_ws, size_t ws_size,
                              hipStream_t stream) {
  const float* x = (const float*)d_in[0];
  const float* Wqkv = (const float*)d_in[1];
  const float* bqkv = (const float*)d_in[2];
  const float* Wm = (const float*)d_in[3];
  const float* bm = (const float*)d_in[4];
  const float* rel = (const float*)d_in[5];

  const size_t M = 131072;  // B*G*P
  char* ws = (char*)d_ws;
  size_t off = 0;
  unsigned short* xb = (unsigned short*)(ws + off);    off += M * 384 * 2;  // 100 MB
  unsigned short* WqkvT = (unsigned short*)(ws + off); off += 1152 * 384 * 2;
  unsigned short* WmT = (unsigned short*)(ws + off);   off += 384 * 384 * 2;
  float* biasF = (float*)(ws + off);                   off += 12 * 16 * 64 * 4 * 4;
  float* bqkvs = (float*)(ws + off);                   off += 1152 * 4;

  if (ws_size < off) {
    fill_val<<<(out_size + 255) / 256, 256, 0, stream>>>((float*)d_out, out_size, 12345.0f);
    return;
  }

  prep_all<<<4401, 256, 0, stream>>>(x, xb, Wqkv, WqkvT, Wm, WmT, bqkv, bqkvs, rel, biasF);
  fused_k<<<2048, 768, 0, stream>>>(xb, WqkvT, bqkvs, biasF, WmT, bm, (float*)d_out);
}

// Round 20
// 424.836 us; speedup vs baseline: 1.6339x; 1.5632x over previous
//
#include <hip/hip_runtime.h>
#include <stdint.h>

// Round 20: REVERT to R15 verbatim (verified best: 424us). The full-fusion arc
// (R17-R19) is abandoned: compiler pins VGPR=84 for 768-thread blocks (budgets
// for 2 blocks/CU despite 149KB LDS), spilling 0.6-1.4GB scratch; launch_bounds
// and structural live-state reduction both failed to move it.
// Pipeline: prep_all (merged conv+weights+bias) -> gemm1 (counted-vmcnt dbuf +
// T2 swizzle + coalesced qkv epilogue) -> fused attn+gemm2 (12 waves/window,
// one barrier, R14 4-lane-transposed LDS stores).

typedef __attribute__((ext_vector_type(4))) float f32x4;
typedef __attribute__((ext_vector_type(4))) short s16x4;
typedef __attribute__((ext_vector_type(8))) short s16x8;

#define DEVI static __device__ __forceinline__

DEVI unsigned short f2bf(float f) {
  union { float f; uint32_t u; } v; v.f = f;
  return (unsigned short)((v.u + 0x7FFFu + ((v.u >> 16) & 1u)) >> 16);
}

DEVI uint32_t pk2(float lo, float hi) {
  return (uint32_t)f2bf(lo) | ((uint32_t)f2bf(hi) << 16);
}

DEVI f32x4 zero4() { f32x4 z; z[0] = 0.f; z[1] = 0.f; z[2] = 0.f; z[3] = 0.f; return z; }

#if defined(__has_builtin)
#if __has_builtin(__builtin_amdgcn_mfma_f32_16x16x16bf16_1k)
#define MFMA16_BUILTIN 1
#endif
#if __has_builtin(__builtin_amdgcn_global_load_lds)
#define HAS_GLLDS 1
#endif
#endif

DEVI f32x4 mfma16(s16x4 a, s16x4 b, f32x4 c) {
#ifdef MFMA16_BUILTIN
  return __builtin_amdgcn_mfma_f32_16x16x16bf16_1k(a, b, c, 0, 0, 0);
#else
  asm volatile("v_mfma_f32_16x16x16_bf16 %0, %1, %2, %0" : "+v"(c) : "v"(a), "v"(b));
  return c;
#endif
}

DEVI f32x4 mfma32(s16x8 a, s16x8 b, f32x4 c) {
  return __builtin_amdgcn_mfma_f32_16x16x32_bf16(a, b, c, 0, 0, 0);
}

DEVI void stage1k(const unsigned short* g_lane, unsigned short* lds_base) {
#ifdef HAS_GLLDS
  __builtin_amdgcn_global_load_lds(
      (const __attribute__((address_space(1))) unsigned int*)g_lane,
      (__attribute__((address_space(3))) unsigned int*)lds_base, 16, 0, 0);
#else
  *(s16x8*)(lds_base + (threadIdx.x & 63) * 8) = *(const s16x8*)g_lane;
#endif
}

__global__ void fill_val(float* o, int n, float v) {
  int t = blockIdx.x * 256 + threadIdx.x;
  if (t < n) o[t] = v;
}

// ---------------- merged prep (R13 verbatim) ----------------
__global__ __launch_bounds__(256) void prep_all(
    const float* __restrict__ x, unsigned short* __restrict__ xb,
    const float* __restrict__ Wqkv, unsigned short* __restrict__ WqkvT,
    const float* __restrict__ Wm, unsigned short* __restrict__ WmT,
    const float* __restrict__ bqkv, float* __restrict__ bqkvs,
    const float* __restrict__ rel, float* __restrict__ biasF) {
  const int b = blockIdx.x;
  if (b < 2048) {
    const size_t nchunk = 131072UL * 384 / 8;
    for (size_t i = (size_t)b * 256 + threadIdx.x; i < nchunk; i += 2048UL * 256) {
      f32x4 a = *(const f32x4*)(x + i * 8);
      f32x4 c = *(const f32x4*)(x + i * 8 + 4);
      s16x8 p;
      p[0] = (short)f2bf(a[0]); p[1] = (short)f2bf(a[1]);
      p[2] = (short)f2bf(a[2]); p[3] = (short)f2bf(a[3]);
      p[4] = (short)f2bf(c[0]); p[5] = (short)f2bf(c[1]);
      p[6] = (short)f2bf(c[2]); p[7] = (short)f2bf(c[3]);
      *(s16x8*)(xb + i * 8) = p;
    }
  } else if (b == 2048) {
    for (int t = threadIdx.x; t < 1152; t += 256)
      bqkvs[t] = bqkv[t] * ((t < 384) ? 0.17677669529663687f : 1.0f);
  } else if (b < 2097) {
    int t = (b - 2049) * 256 + threadIdx.x;  // 12288
    if (t < 12288) {
      int h = t >> 10;
      int r = (t >> 6) & 15;
      int lane = t & 63;
      int jt = r >> 2, it = r & 3;
      int lg = lane >> 4, lr = lane & 15;
      int i = it * 16 + lr;
#pragma unroll
      for (int e = 0; e < 4; ++e) {
        int j = jt * 16 + lg * 4 + e;
        int idx = ((i >> 3) - (j >> 3) + 7) * 15 + ((i & 7) - (j & 7) + 7);
        biasF[t * 4 + e] = rel[idx * 12 + h];
      }
    }
  } else if (b < 2673) {
    int t = (b - 2097) * 256 + threadIdx.x;  // 147456
    int n = t / 384, k = t - n * 384;
    WmT[t] = f2bf(Wm[(size_t)k * 384 + n]);
  } else {
    int t = (b - 2673) * 256 + threadIdx.x;  // 442368
    int n = t / 384, k = t - n * 384;
    float s = (n < 384) ? 0.17677669529663687f : 1.0f;
    WqkvT[t] = f2bf(Wqkv[(size_t)k * 1152 + n] * s);
  }
}

// ---------------- GEMM1 (R12 verbatim, counted-vmcnt dbuf + T2 swizzle) ----------
template <bool QKV_EPI>
__global__ __launch_bounds__(512, 4) void gemm_k(const unsigned short* __restrict__ A,
                                                 const unsigned short* __restrict__ BT,
                                                 const float* __restrict__ bias,
                                                 void* __restrict__ Cv) {
  constexpr int K = 384;
  constexpr int NT = QKV_EPI ? 9 : 3;
  constexpr int N = NT * 128;
  __shared__ unsigned short sm[2][16384];
  const int bid = blockIdx.x;
  const int swz = (bid & 7) * (NT * 128) + (bid >> 3);
  const int n0 = (swz % NT) * 128;
  const int m0 = (swz / NT) * 128;
  const int tid = threadIdx.x;
  const int lane = tid & 63, wv = tid >> 6;
  const int wr = wv >> 2, wc = wv & 3;
  const int lg = lane >> 4, lr = lane & 15;

  const int scol = ((lane & 7) ^ (lane >> 3)) * 8;
  const unsigned short* Ag = A + (size_t)(m0 + wv * 16 + (lane >> 3)) * K + scol;
  const unsigned short* Bg = BT + (size_t)(n0 + wv * 16 + (lane >> 3)) * K + scol;

  f32x4 acc[4][2];
#pragma unroll
  for (int i = 0; i < 4; ++i)
#pragma unroll
    for (int j = 0; j < 2; ++j) acc[i][j] = zero4();

  auto STAGE = [&](int buf, int k0) {
#pragma unroll
    for (int c2 = 0; c2 < 2; ++c2)
      stage1k(Ag + (size_t)(c2 * 8) * K + k0, &sm[buf][(wv * 16 + c2 * 8) * 64]);
#pragma unroll
    for (int c2 = 0; c2 < 2; ++c2)
      stage1k(Bg + (size_t)(c2 * 8) * K + k0, &sm[buf][8192 + (wv * 16 + c2 * 8) * 64]);
  };
  const int sa = (lr & 7) << 3;
  auto COMPUTE = [&](int buf) {
#pragma unroll
    for (int kk = 0; kk < 64; kk += 32) {
      s16x8 af[4], bf[2];
#pragma unroll
      for (int mt = 0; mt < 4; ++mt)
        af[mt] = *(const s16x8*)&sm[buf][(wr * 64 + 16 * mt + lr) * 64 + ((kk + 8 * lg) ^ sa)];
#pragma unroll
      for (int nt = 0; nt < 2; ++nt)
        bf[nt] = *(const s16x8*)&sm[buf][8192 + (wc * 32 + 16 * nt + lr) * 64 + ((kk + 8 * lg) ^ sa)];
#pragma unroll
      for (int mt = 0; mt < 4; ++mt)
#pragma unroll
        for (int nt = 0; nt < 2; ++nt)
          acc[mt][nt] = mfma32(af[mt], bf[nt], acc[mt][nt]);
    }
  };

  STAGE(0, 0);
  int cur = 0;
#pragma unroll 1
  for (int t = 0; t < 5; ++t) {
    STAGE(cur ^ 1, (t + 1) * 64);
    asm volatile("s_waitcnt vmcnt(4)" ::: "memory");
    __builtin_amdgcn_sched_barrier(0);
    __builtin_amdgcn_s_barrier();
    __builtin_amdgcn_sched_barrier(0);
    COMPUTE(cur);
    __builtin_amdgcn_sched_barrier(0);
    __builtin_amdgcn_s_barrier();
    cur ^= 1;
  }
  asm volatile("s_waitcnt vmcnt(0)" ::: "memory");
  __builtin_amdgcn_sched_barrier(0);
  __builtin_amdgcn_s_barrier();
  __builtin_amdgcn_sched_barrier(0);
  COMPUTE(cur);

  const int crow = m0 + wr * 64 + 4 * lg;
  const int ccol = n0 + wc * 32 + lr;
  if constexpr (QKV_EPI) {
    const int sel = n0 / 384;
    unsigned short* qkv = (unsigned short*)Cv;
    if (sel < 2) {
      unsigned short* tile = &sm[0][0];
#pragma unroll
      for (int nt = 0; nt < 2; ++nt) {
        const int cc = wc * 32 + 16 * nt + lr;
        const float bv = bias[n0 + cc];
#pragma unroll
        for (int mt = 0; mt < 4; ++mt) {
#pragma unroll
          for (int e = 0; e < 4; ++e) {
            const int r = wr * 64 + 16 * mt + 4 * lg + e;
            tile[r * 128 + (cc ^ ((r & 7) << 3))] = f2bf(acc[mt][nt][e] + bv);
          }
        }
      }
      __syncthreads();
      const int hbase = (n0 - sel * 384) >> 5;
      const int tr = wv * 16 + (lane >> 2);
      const int gtok = m0 + tr;
      const int w2 = gtok >> 6, t0r = gtok & 63;
#pragma unroll
      for (int hh = 0; hh < 4; ++hh) {
        const int chunk = hh * 4 + (lane & 3);
        s16x8 v = *(const s16x8*)&tile[tr * 128 + ((chunk * 8) ^ ((tr & 7) << 3))];
        unsigned short* dst = qkv + (((size_t)w2 * 12 + hbase + hh) * 3 + sel) * 2048 +
                              t0r * 32 + (lane & 3) * 8;
        *(s16x8*)dst = v;
      }
    } else {
      const int window = crow >> 6;
      const int t0 = crow & 63;
#pragma unroll
      for (int nt = 0; nt < 2; ++nt) {
        const int col = ccol + 16 * nt;
        const int hcol = col - 768;
        const int h = hcol >> 5, d = hcol & 31;
        const float bv = bias[col];
        unsigned short* base = qkv + (((size_t)window * 12 + h) * 3 + 2) * 2048;
#pragma unroll
        for (int mt = 0; mt < 4; ++mt) {
          s16x4 pk;
#pragma unroll
          for (int e = 0; e < 4; ++e) pk[e] = (short)f2bf(acc[mt][nt][e] + bv);
          *(s16x4*)&base[d * 64 + t0 + 16 * mt] = pk;
        }
      }
    }
  } else {
    float* C = (float*)Cv;
#pragma unroll
    for (int mt = 0; mt < 4; ++mt)
#pragma unroll
      for (int nt = 0; nt < 2; ++nt) {
        const int col = ccol + 16 * nt;
        const float bv = bias[col];
#pragma unroll
        for (int e = 0; e < 4; ++e)
          C[(size_t)(crow + 16 * mt + e) * N + col] = acc[mt][nt][e] + bv;
      }
  }
}

// ---------------- fused attention + GEMM2: one block per window, 12 waves ----------
__global__ __launch_bounds__(768) void attn_gemm2_k(const unsigned short* __restrict__ qkv,
                                                    const float* __restrict__ biasF,
                                                    const unsigned short* __restrict__ WmT,
                                                    const float* __restrict__ bm,
                                                    float* __restrict__ out) {
  __shared__ unsigned short att_s[64 * 392];  // 50176 B
  const int lane = threadIdx.x & 63;
  const int wv = threadIdx.x >> 6;  // 0..11 = head
  const int window = blockIdx.x;    // [0, 2048)
  const int h = wv;
  const int lg = lane >> 4, lr = lane & 15;

  const unsigned short* hb = qkv + ((size_t)window * 12 + h) * 6144;
  const unsigned short* Qh = hb;
  const unsigned short* Kh = hb + 2048;
  const unsigned short* Vth = hb + 4096;

  s16x8 ka[4], qb[4];
#pragma unroll
  for (int jt = 0; jt < 4; ++jt)
    ka[jt] = *(const s16x8*)&Kh[(jt * 16 + lr) * 32 + 8 * lg];
#pragma unroll
  for (int it = 0; it < 4; ++it)
    qb[it] = *(const s16x8*)&Qh[(it * 16 + lr) * 32 + 8 * lg];

  f32x4 c[4][4];
#pragma unroll
  for (int a = 0; a < 4; ++a)
#pragma unroll
    for (int b2 = 0; b2 < 4; ++b2) c[a][b2] = zero4();

#pragma unroll
  for (int jt = 0; jt < 4; ++jt)
#pragma unroll
    for (int it = 0; it < 4; ++it)
      c[jt][it] = mfma32(ka[jt], qb[it], c[jt][it]);

  const f32x4* bF = (const f32x4*)biasF + ((size_t)h * 16) * 64 + lane;
#pragma unroll
  for (int jt = 0; jt < 4; ++jt)
#pragma unroll
    for (int it = 0; it < 4; ++it)
      c[jt][it] += bF[(jt * 4 + it) * 64];

  s16x4 pb[4][4];
#pragma unroll
  for (int it = 0; it < 4; ++it) {
    float m = -3.0e38f;
#pragma unroll
    for (int jt = 0; jt < 4; ++jt)
#pragma unroll
      for (int e = 0; e < 4; ++e) m = fmaxf(m, c[jt][it][e]);
    m = fmaxf(m, __shfl_xor(m, 16));
    m = fmaxf(m, __shfl_xor(m, 32));
    float s = 0.f;
#pragma unroll
    for (int jt = 0; jt < 4; ++jt)
#pragma unroll
      for (int e = 0; e < 4; ++e) {
        float p = __expf(c[jt][it][e] - m);
        c[jt][it][e] = p;
        s += p;
      }
    s += __shfl_xor(s, 16);
    s += __shfl_xor(s, 32);
    const float inv = 1.f / s;
#pragma unroll
    for (int jt = 0; jt < 4; ++jt) {
      s16x4 pk;
#pragma unroll
      for (int e = 0; e < 4; ++e) pk[e] = (short)f2bf(c[jt][it][e] * inv);
      pb[jt][it] = pk;
    }
  }

  f32x4 o[2][4];
#pragma unroll
  for (int a = 0; a < 2; ++a)
#pragma unroll
    for (int b2 = 0; b2 < 4; ++b2) o[a][b2] = zero4();

#pragma unroll
  for (int jt = 0; jt < 4; ++jt) {
    s16x4 va[2];
#pragma unroll
    for (int dt = 0; dt < 2; ++dt)
      va[dt] = *(const s16x4*)&Vth[(dt * 16 + lr) * 64 + jt * 16 + 4 * lg];
#pragma unroll
    for (int dt = 0; dt < 2; ++dt)
#pragma unroll
      for (int it = 0; it < 4; ++it)
        o[dt][it] = mfma16(va[dt], pb[jt][it], o[dt][it]);
  }

  // R14 4-lane transpose -> LDS: lane lg holds d[8lg,8lg+8) of token it*16+lr.
#pragma unroll
  for (int it = 0; it < 4; ++it) {
    const uint32_t p0 = pk2(o[0][it][0], o[0][it][1]);
    const uint32_t p1 = pk2(o[0][it][2], o[0][it][3]);
    const uint32_t q0 = pk2(o[1][it][0], o[1][it][1]);
    const uint32_t q1 = pk2(o[1][it][2], o[1][it][3]);

    const uint32_t x16_0 = __shfl_xor((int)(lg == 2 ? q0 : p0), 16);
    const uint32_t x16_1 = __shfl_xor((int)(lg == 2 ? q1 : p1), 16);
    const uint32_t x32_0 = __shfl_xor((int)(lg == 0 ? q0 : p0), 32);
    const uint32_t x32_1 = __shfl_xor((int)(lg == 0 ? q1 : p1), 32);
    const uint32_t x48_0 = __shfl_xor((int)(lg == 1 ? q0 : p0), 48);
    const uint32_t x48_1 = __shfl_xor((int)(lg == 1 ? q1 : p1), 48);

    uint32_t w[4];
    w[0] = lg == 0 ? p0 : lg == 1 ? x48_0 : lg == 2 ? x32_0 : x16_0;
    w[1] = lg == 0 ? p1 : lg == 1 ? x48_1 : lg == 2 ? x32_1 : x16_1;
    w[2] = lg == 0 ? x16_0 : lg == 1 ? x32_0 : lg == 2 ? x48_0 : q0;
    w[3] = lg == 0 ? x16_1 : lg == 1 ? x32_1 : lg == 2 ? x48_1 : q1;

    *(uint4*)&att_s[(size_t)(it * 16 + lr) * 392 + h * 32 + 8 * lg] =
        make_uint4(w[0], w[1], w[2], w[3]);
  }

  __syncthreads();

  // ---- phase 2: GEMM2. wave wv -> output cols [wv*32, wv*32+32)
  f32x4 acc[4][2];
#pragma unroll
  for (int mt = 0; mt < 4; ++mt)
#pragma unroll
    for (int nt = 0; nt < 2; ++nt) acc[mt][nt] = zero4();

  const int n0w = wv * 32;
#pragma unroll 2
  for (int ks = 0; ks < 12; ++ks) {
    s16x8 af[4], bf[2];
#pragma unroll
    for (int mt = 0; mt < 4; ++mt)
      af[mt] = *(const s16x8*)&att_s[(16 * mt + lr) * 392 + ks * 32 + 8 * lg];
#pragma unroll
    for (int nt = 0; nt < 2; ++nt)
      bf[nt] = *(const s16x8*)&WmT[(size_t)(n0w + 16 * nt + lr) * 384 + ks * 32 + 8 * lg];
#pragma unroll
    for (int mt = 0; mt < 4; ++mt)
#pragma unroll
      for (int nt = 0; nt < 2; ++nt)
        acc[mt][nt] = mfma32(af[mt], bf[nt], acc[mt][nt]);
  }

  float* ob = out + (size_t)window * 64 * 384;
#pragma unroll
  for (int mt = 0; mt < 4; ++mt)
#pragma unroll
    for (int nt = 0; nt < 2; ++nt) {
      const int col = n0w + 16 * nt + lr;
      const float bv = bm[col];
#pragma unroll
      for (int e = 0; e < 4; ++e)
        ob[(size_t)(16 * mt + 4 * lg + e) * 384 + col] = acc[mt][nt][e] + bv;
    }
}

extern "C" void kernel_launch(void* const* d_in, const int* in_sizes, int n_in,
                              void* d_out, int out_size, void* d_ws, size_t ws_size,
                              hipStream_t stream) {
  const float* x = (const float*)d_in[0];
  const float* Wqkv = (const float*)d_in[1];
  const float* bqkv = (const float*)d_in[2];
  const float* Wm = (const float*)d_in[3];
  const float* bm = (const float*)d_in[4];
  const float* rel = (const float*)d_in[5];

  const size_t M = 131072;  // B*G*P
  char* ws = (char*)d_ws;
  size_t off = 0;
  unsigned short* qkv = (unsigned short*)(ws + off);   off += M * 1152 * 2;  // 302 MB
  unsigned short* xb = (unsigned short*)(ws + off);    off += M * 384 * 2;   // 100 MB
  unsigned short* WqkvT = (unsigned short*)(ws + off); off += 1152 * 384 * 2;
  unsigned short* WmT = (unsigned short*)(ws + off);   off += 384 * 384 * 2;
  float* biasF = (float*)(ws + off);                   off += 12 * 16 * 64 * 4 * 4;
  float* bqkvs = (float*)(ws + off);                   off += 1152 * 4;

  if (ws_size < off) {
    fill_val<<<(out_size + 255) / 256, 256, 0, stream>>>((float*)d_out, out_size, 12345.0f);
    return;
  }

  prep_all<<<4401, 256, 0, stream>>>(x, xb, Wqkv, WqkvT, Wm, WmT, bqkv, bqkvs, rel, biasF);
  gemm_k<true><<<9216, 512, 0, stream>>>(xb, WqkvT, bqkvs, qkv);
  attn_gemm2_k<<<2048, 768, 0, stream>>>(qkv, biasF, WmT, bm, (float*)d_out);
}